// Round 1
// baseline (943.010 us; speedup 1.0000x reference)
//
#include <hip/hip_runtime.h>
#include <math.h>

#define NB 4
#define NHP 128
#define NWP 128
#define NC 256
#define NTOK (NHP*NWP)      // 16384
#define MTOT (NB*NTOK)      // 65536
#define NHEADS 8
#define DHEAD 32

// ---------------- 64x64 tiled fp32 GEMM body: O[row0.., col0..] = A[M,256] @ Wt[256,256] (+bias) ----------------
__device__ __forceinline__ void gemm64x64(const float* __restrict__ A,
                                          const float* __restrict__ Wt,
                                          const float* __restrict__ bias,
                                          float* __restrict__ O,
                                          int row0, int col0)
{
  __shared__ float As[16][64];
  __shared__ float Bs[16][64];
  const int t  = threadIdx.x;
  const int tx = t & 15, ty = t >> 4;
  const int ar = t >> 2,  ak = (t & 3) << 2;   // A stage: row, k-quad
  const int bk = t >> 4,  bn = (t & 15) << 2;  // B stage: k, n-quad
  float acc[4][4];
#pragma unroll
  for (int i = 0; i < 4; ++i)
#pragma unroll
    for (int j = 0; j < 4; ++j) acc[i][j] = 0.f;

  for (int k0 = 0; k0 < 256; k0 += 16) {
    float4 av = *(const float4*)&A[(size_t)(row0 + ar) * NC + k0 + ak];
    float4 bv = *(const float4*)&Wt[(size_t)(k0 + bk) * NC + col0 + bn];
    As[ak + 0][ar] = av.x; As[ak + 1][ar] = av.y; As[ak + 2][ar] = av.z; As[ak + 3][ar] = av.w;
    *(float4*)&Bs[bk][bn] = bv;
    __syncthreads();
#pragma unroll
    for (int k = 0; k < 16; ++k) {
      float4 a4 = *(const float4*)&As[k][ty << 2];
      float4 b4 = *(const float4*)&Bs[k][tx << 2];
      float aa[4] = {a4.x, a4.y, a4.z, a4.w};
      float bb[4] = {b4.x, b4.y, b4.z, b4.w};
#pragma unroll
      for (int i = 0; i < 4; ++i)
#pragma unroll
        for (int j = 0; j < 4; ++j)
          acc[i][j] = fmaf(aa[i], bb[j], acc[i][j]);
    }
    __syncthreads();
  }
#pragma unroll
  for (int i = 0; i < 4; ++i) {
    float4 o4 = make_float4(acc[i][0], acc[i][1], acc[i][2], acc[i][3]);
    if (bias) {
      float4 b4 = *(const float4*)&bias[col0 + (tx << 2)];
      o4.x += b4.x; o4.y += b4.y; o4.z += b4.z; o4.w += b4.w;
    }
    *(float4*)&O[(size_t)(row0 + (ty << 2) + i) * NC + col0 + (tx << 2)] = o4;
  }
}

__global__ __launch_bounds__(256) void qkv_gemm(const float* __restrict__ X, const float* __restrict__ Y,
                                                const float* __restrict__ F, const float* __restrict__ Wq,
                                                const float* __restrict__ Wk, const float* __restrict__ Wv,
                                                float* __restrict__ Q, float* __restrict__ K,
                                                float* __restrict__ V)
{
  const float* A; const float* Wt; float* O;
  switch (blockIdx.z) {
    case 0:  A = X; Wt = Wq; O = Q; break;
    case 1:  A = Y; Wt = Wk; O = K; break;
    default: A = F; Wt = Wv; O = V; break;
  }
  gemm64x64(A, Wt, nullptr, O, blockIdx.x * 64, blockIdx.y * 64);
}

__global__ __launch_bounds__(256) void out_gemm(const float* __restrict__ V, const float* __restrict__ Weff,
                                                const float* __restrict__ bp, float* __restrict__ Out)
{
  int row0 = blockIdx.x * 64;
  int b = row0 >> 14;                 // 16384 rows per batch
  gemm64x64(V, Weff + (size_t)b * NC * NC, bp, Out, row0, blockIdx.y * 64);
}

// ---------------- Gram matrix G[b,h,i,j] = sum_n K[b,n,h*32+i]*Q[b,n,h*32+j]  + norms ----------------
__global__ __launch_bounds__(256) void gram(const float* __restrict__ Q, const float* __restrict__ K,
                                            float* __restrict__ G, float* __restrict__ qn,
                                            float* __restrict__ kn)
{
  const int bh = blockIdx.x;          // 0..31
  const int b = bh >> 3, h = bh & 7;
  const int n0 = blockIdx.y << 11;    // chunks of 2048 rows
  const float* Qb = Q + (size_t)b * NTOK * NC + h * DHEAD;
  const float* Kb = K + (size_t)b * NTOK * NC + h * DHEAD;
  __shared__ float qs[64][32];
  __shared__ float ks[64][32];
  const int t = threadIdx.x;
  const int i = t >> 3;               // 0..31 (k-row of G)
  const int j4 = (t & 7) << 2;        // 0,4,..28 (q-col quad)
  float acc[4] = {0.f, 0.f, 0.f, 0.f};
  float q2[4] = {0.f, 0.f, 0.f, 0.f};
  float k2 = 0.f;
  for (int nb = 0; nb < 2048; nb += 64) {
#pragma unroll
    for (int l = 0; l < 2; ++l) {
      int idx = t + (l << 8);         // 0..511 float4 slots
      int r = idx >> 3;
      int cc = (idx & 7) << 2;
      *(float4*)&qs[r][cc] = *(const float4*)&Qb[(size_t)(n0 + nb + r) * NC + cc];
      *(float4*)&ks[r][cc] = *(const float4*)&Kb[(size_t)(n0 + nb + r) * NC + cc];
    }
    __syncthreads();
#pragma unroll 4
    for (int r = 0; r < 64; ++r) {
      float kv = ks[r][i];
      float4 qv = *(const float4*)&qs[r][j4];
      acc[0] = fmaf(kv, qv.x, acc[0]);
      acc[1] = fmaf(kv, qv.y, acc[1]);
      acc[2] = fmaf(kv, qv.z, acc[2]);
      acc[3] = fmaf(kv, qv.w, acc[3]);
      if (i == 0) {
        q2[0] = fmaf(qv.x, qv.x, q2[0]); q2[1] = fmaf(qv.y, qv.y, q2[1]);
        q2[2] = fmaf(qv.z, qv.z, q2[2]); q2[3] = fmaf(qv.w, qv.w, q2[3]);
      }
      if ((t & 7) == 0) k2 = fmaf(kv, kv, k2);
    }
    __syncthreads();
  }
  float* Gb = G + (size_t)(b * NHEADS + h) * DHEAD * DHEAD;
  atomicAdd(&Gb[i * DHEAD + j4 + 0], acc[0]);
  atomicAdd(&Gb[i * DHEAD + j4 + 1], acc[1]);
  atomicAdd(&Gb[i * DHEAD + j4 + 2], acc[2]);
  atomicAdd(&Gb[i * DHEAD + j4 + 3], acc[3]);
  if (i == 0) {
#pragma unroll
    for (int u = 0; u < 4; ++u) atomicAdd(&qn[b * NC + h * DHEAD + j4 + u], q2[u]);
  }
  if ((t & 7) == 0) atomicAdd(&kn[b * NC + h * DHEAD + i], k2);
}

// ---------------- softmax(G/denominator * rescale) then Weff[b, h*32+j, m] = sum_i A[h,i,j]*Wp[h*32+i, m] ----------------
__global__ __launch_bounds__(256) void softmax_weff(const float* __restrict__ G, const float* __restrict__ qn,
                                                    const float* __restrict__ kn, const float* __restrict__ rescale,
                                                    const float* __restrict__ Wp, float* __restrict__ Weff)
{
  const int b = blockIdx.x, h = blockIdx.y;
  __shared__ float Asm[32][33];       // padded: rows read column-wise in softmax
  __shared__ float WpS[32][256];
  const int t = threadIdx.x;
  const float rs = rescale[h];
  const float* Gb = G + (size_t)(b * NHEADS + h) * DHEAD * DHEAD;
#pragma unroll
  for (int l = 0; l < 4; ++l) {
    int idx = t + (l << 8);
    int i = idx >> 5, j = idx & 31;
    float knv = fmaxf(sqrtf(kn[b * NC + h * DHEAD + i]), 1e-12f);
    float qnv = fmaxf(sqrtf(qn[b * NC + h * DHEAD + j]), 1e-12f);
    Asm[i][j] = Gb[idx] / (knv * qnv) * rs;
  }
  __syncthreads();
  if (t < 32) {                       // row-wise softmax over j (32 rows; tiny)
    int i = t;
    float mx = -1e30f;
#pragma unroll
    for (int j = 0; j < 32; ++j) mx = fmaxf(mx, Asm[i][j]);
    float s = 0.f;
#pragma unroll
    for (int j = 0; j < 32; ++j) { float e = __expf(Asm[i][j] - mx); Asm[i][j] = e; s += e; }
    float inv = 1.f / s;
#pragma unroll
    for (int j = 0; j < 32; ++j) Asm[i][j] *= inv;
  }
  // stage Wp rows [h*32, h*32+32) x 256
#pragma unroll
  for (int l = 0; l < 8; ++l) {
    int idx = t + (l << 8);           // float4 slot 0..2047
    int r = idx >> 6;
    int c4 = (idx & 63) << 2;
    *(float4*)&WpS[r][c4] = *(const float4*)&Wp[(size_t)(h * DHEAD + r) * NC + c4];
  }
  __syncthreads();
  const int j = t & 31, mb = t >> 5;
  for (int mm = 0; mm < 32; ++mm) {
    int m = (mb << 5) + mm;
    float s = 0.f;
#pragma unroll
    for (int i = 0; i < 32; ++i) s = fmaf(Asm[i][j], WpS[i][m], s);
    Weff[((size_t)b * NC + h * DHEAD + j) * NC + m] = s;
  }
}

// ---------------- depthwise 3x3 (NHWC) + exact GELU ----------------
__global__ __launch_bounds__(256) void dw1_gelu(const float* __restrict__ Vi, const float* __restrict__ pw1,
                                                float* __restrict__ T)
{
  int idx = blockIdx.x * 256 + threadIdx.x;
  int c = idx & 255;
  int x = (idx >> 8) & 127;
  int y = (idx >> 15) & 127;
  int b = idx >> 22;
  float acc = 0.f;
#pragma unroll
  for (int ky = 0; ky < 3; ++ky) {
    int yy = y + ky - 1;
    if ((unsigned)yy >= 128u) continue;
#pragma unroll
    for (int kx = 0; kx < 3; ++kx) {
      int xx = x + kx - 1;
      if ((unsigned)xx >= 128u) continue;
      acc = fmaf(Vi[((size_t)((b * 128 + yy) * 128) + xx) * 256 + c], pw1[(ky * 3 + kx) * 256 + c], acc);
    }
  }
  T[idx] = 0.5f * acc * (1.f + erff(acc * 0.70710678118654752f));
}

__global__ __launch_bounds__(256) void dw2_add(const float* __restrict__ T, const float* __restrict__ pw2,
                                               float* __restrict__ Out)
{
  int idx = blockIdx.x * 256 + threadIdx.x;
  int c = idx & 255;
  int x = (idx >> 8) & 127;
  int y = (idx >> 15) & 127;
  int b = idx >> 22;
  float acc = 0.f;
#pragma unroll
  for (int ky = 0; ky < 3; ++ky) {
    int yy = y + ky - 1;
    if ((unsigned)yy >= 128u) continue;
#pragma unroll
    for (int kx = 0; kx < 3; ++kx) {
      int xx = x + kx - 1;
      if ((unsigned)xx >= 128u) continue;
      acc = fmaf(T[((size_t)((b * 128 + yy) * 128) + xx) * 256 + c], pw2[(ky * 3 + kx) * 256 + c], acc);
    }
  }
  Out[idx] += acc;
}

extern "C" void kernel_launch(void* const* d_in, const int* in_sizes, int n_in,
                              void* d_out, int out_size, void* d_ws, size_t ws_size,
                              hipStream_t stream)
{
  const float* x   = (const float*)d_in[0];
  const float* y   = (const float*)d_in[1];
  const float* f   = (const float*)d_in[2];
  const float* Wq  = (const float*)d_in[3];
  const float* Wk  = (const float*)d_in[4];
  const float* Wv  = (const float*)d_in[5];
  const float* rsc = (const float*)d_in[6];
  const float* Wp  = (const float*)d_in[7];
  const float* bp  = (const float*)d_in[8];
  const float* pw1 = (const float*)d_in[9];
  const float* pw2 = (const float*)d_in[10];
  float* out = (float*)d_out;

  float* ws = (float*)d_ws;
  size_t off = 0;
  float* Qi = ws + off; off += (size_t)MTOT * NC;                 // 16.78M
  float* Ki = ws + off; off += (size_t)MTOT * NC;
  float* Vi = ws + off; off += (size_t)MTOT * NC;
  float* G  = ws + off; off += (size_t)NB * NHEADS * DHEAD * DHEAD; // 32768
  float* qn = ws + off; off += NB * NC;                           // 1024
  float* kn = ws + off; off += NB * NC;                           // 1024
  float* Weff = ws + off; off += (size_t)NB * NC * NC;            // 262144
  float* T = Qi;  // reuse q_inp storage after gram() consumed it

  // zero the atomic accumulators (G, qn, kn are contiguous)
  hipMemsetAsync(G, 0, (size_t)(NB * NHEADS * DHEAD * DHEAD + 2 * NB * NC) * sizeof(float), stream);

  qkv_gemm<<<dim3(MTOT / 64, NC / 64, 3), 256, 0, stream>>>(x, y, f, Wq, Wk, Wv, Qi, Ki, Vi);
  gram<<<dim3(32, 8), 256, 0, stream>>>(Qi, Ki, G, qn, kn);
  softmax_weff<<<dim3(NB, NHEADS), 256, 0, stream>>>(G, qn, kn, rsc, Wp, Weff);
  dw1_gelu<<<(size_t)MTOT * NC / 256, 256, 0, stream>>>(Vi, pw1, T);
  out_gemm<<<dim3(MTOT / 64, NC / 64), 256, 0, stream>>>(Vi, Weff, bp, out);
  dw2_add<<<(size_t)MTOT * NC / 256, 256, 0, stream>>>(T, pw2, out);
}

// Round 3
// 492.944 us; speedup vs baseline: 1.9130x; 1.9130x over previous
//
#include <hip/hip_runtime.h>
#include <math.h>

#define NB 4
#define NC 256
#define NTOK 16384
#define MTOT 65536
#define NHEADS 8
#define DHEAD 32

typedef __attribute__((ext_vector_type(4))) float f32x4;
typedef __attribute__((ext_vector_type(8))) short short8;

__device__ __forceinline__ unsigned short bfbits(float f) {
  unsigned u = __builtin_bit_cast(unsigned, f);
  unsigned r = (u + 0x7FFFu + ((u >> 16) & 1u)) >> 16;
  return (unsigned short)r;
}
__device__ __forceinline__ float bflo(unsigned w) { return __builtin_bit_cast(float, w << 16); }
__device__ __forceinline__ float bfhi(unsigned w) { return __builtin_bit_cast(float, w & 0xFFFF0000u); }

__device__ __forceinline__ short8 pack8(float4 a, float4 b) {
  short8 s;
  s[0] = (short)bfbits(a.x); s[1] = (short)bfbits(a.y); s[2] = (short)bfbits(a.z); s[3] = (short)bfbits(a.w);
  s[4] = (short)bfbits(b.x); s[5] = (short)bfbits(b.y); s[6] = (short)bfbits(b.z); s[7] = (short)bfbits(b.w);
  return s;
}

// ---------- weight transpose+convert: W[k][n] fp32 -> WT[n][k] bf16 ----------
__global__ __launch_bounds__(256) void prep_w(const float* __restrict__ Wq, const float* __restrict__ Wk,
                                              const float* __restrict__ Wv, unsigned short* __restrict__ WT)
{
  const float* W = (blockIdx.z == 0) ? Wq : (blockIdx.z == 1) ? Wk : Wv;
  unsigned short* O = WT + (size_t)blockIdx.z * NC * NC;
  __shared__ float tile[64][65];
  const int k0 = blockIdx.x * 64, n0 = blockIdx.y * 64;
  const int t = threadIdx.x;
  {
    int r = t >> 2, cq = (t & 3) << 4;
#pragma unroll
    for (int i = 0; i < 16; i += 4) {
      float4 v = *(const float4*)&W[(size_t)(k0 + r) * NC + n0 + cq + i];
      tile[r][cq + i + 0] = v.x; tile[r][cq + i + 1] = v.y;
      tile[r][cq + i + 2] = v.z; tile[r][cq + i + 3] = v.w;
    }
  }
  __syncthreads();
  int n = t >> 2, kq = (t & 3) << 4;
  short8 s0, s1;
#pragma unroll
  for (int i = 0; i < 8; ++i) s0[i] = (short)bfbits(tile[kq + i][n]);
#pragma unroll
  for (int i = 0; i < 8; ++i) s1[i] = (short)bfbits(tile[kq + 8 + i][n]);
  *(short8*)&O[(size_t)(n0 + n) * NC + k0 + kq] = s0;
  *(short8*)&O[(size_t)(n0 + n) * NC + k0 + kq + 8] = s1;
}

// ---------- MFMA GEMM core: C[128 x 256] = A[128 x 256] * Bt^T, bf16 in, fp32 acc ----------
// LDS: As[128][64] bf16 (16KB, XOR-swizzled) + Bs[256][64] bf16 (32KB, swizzled)
template<bool SRCF32>
__device__ __forceinline__ void gemm_core(const float* __restrict__ Af,
                                          const unsigned short* __restrict__ Ab,
                                          const unsigned short* __restrict__ Bt,
                                          int row0, char* __restrict__ smem,
                                          f32x4 (&acc)[4][4])
{
  const int t = threadIdx.x;
  const int lane = t & 63;
  const int wid = t >> 6;
  const int wm = (wid >> 2) << 6;   // 0 / 64
  const int wn = (wid & 3) << 6;    // 0..192
  const int ar = t >> 2;            // A stage row 0..127
  const int ak = (t & 3) << 4;      // A stage k elem start
  const int br = t >> 1;            // B stage row 0..255
  const int bkb = (t & 1) << 6;     // B stage k byte start (0/64)
  const int swza = (ar & 7) << 4;
  const int swzb = (br & 7) << 4;
  const int g16 = (lane >> 4) << 4; // fragment k byte offset
  const int fr = lane & 15;

  int arow[4], brow[4];
#pragma unroll
  for (int m = 0; m < 4; ++m) arow[m] = wm + m * 16 + fr;
#pragma unroll
  for (int n = 0; n < 4; ++n) brow[n] = wn + n * 16 + fr;

#pragma unroll
  for (int m = 0; m < 4; ++m)
#pragma unroll
    for (int n = 0; n < 4; ++n) acc[m][n] = f32x4{0.f, 0.f, 0.f, 0.f};

  const int aSt = ar * 128;
  const int bSt = 16384 + br * 128;

  for (int k0 = 0; k0 < 256; k0 += 64) {
    // stage A (fp32 -> bf16 convert, or bf16 passthrough)
    short8 s0, s1;
    if (SRCF32) {
      const float* ap = Af + (size_t)(row0 + ar) * NC + k0 + ak;
      float4 f0 = *(const float4*)(ap);
      float4 f1 = *(const float4*)(ap + 4);
      float4 f2 = *(const float4*)(ap + 8);
      float4 f3 = *(const float4*)(ap + 12);
      s0 = pack8(f0, f1); s1 = pack8(f2, f3);
    } else {
      const unsigned short* ap = Ab + (size_t)(row0 + ar) * NC + k0 + ak;
      s0 = *(const short8*)(ap);
      s1 = *(const short8*)(ap + 8);
    }
    *(short8*)(smem + aSt + ((ak * 2) ^ swza)) = s0;
    *(short8*)(smem + aSt + ((ak * 2 + 16) ^ swza)) = s1;
    // stage B (bf16 pre-transposed)
    {
      const unsigned short* bp = Bt + (size_t)br * NC + k0 + (bkb >> 1);
      short8 b0 = *(const short8*)(bp);
      short8 b1 = *(const short8*)(bp + 8);
      short8 b2 = *(const short8*)(bp + 16);
      short8 b3 = *(const short8*)(bp + 24);
      *(short8*)(smem + bSt + ((bkb) ^ swzb)) = b0;
      *(short8*)(smem + bSt + ((bkb + 16) ^ swzb)) = b1;
      *(short8*)(smem + bSt + ((bkb + 32) ^ swzb)) = b2;
      *(short8*)(smem + bSt + ((bkb + 48) ^ swzb)) = b3;
    }
    __syncthreads();
#pragma unroll
    for (int ks2 = 0; ks2 < 128; ks2 += 64) {   // ks2 = 2*ks (byte offset of k-half)
      short8 afr[4], bfr[4];
#pragma unroll
      for (int m = 0; m < 4; ++m)
        afr[m] = *(const short8*)(smem + arow[m] * 128 + ((ks2 + g16) ^ ((arow[m] & 7) << 4)));
#pragma unroll
      for (int n = 0; n < 4; ++n)
        bfr[n] = *(const short8*)(smem + 16384 + brow[n] * 128 + ((ks2 + g16) ^ ((brow[n] & 7) << 4)));
#pragma unroll
      for (int m = 0; m < 4; ++m)
#pragma unroll
        for (int n = 0; n < 4; ++n)
          acc[m][n] = __builtin_amdgcn_mfma_f32_16x16x32_bf16(afr[m], bfr[n], acc[m][n], 0, 0, 0);
    }
    __syncthreads();
  }
}

__global__ __launch_bounds__(512) void qkv_mfma(const float* __restrict__ X, const float* __restrict__ Y,
                                                const float* __restrict__ F, const unsigned short* __restrict__ WT,
                                                unsigned short* __restrict__ Qb, unsigned short* __restrict__ Kb,
                                                unsigned short* __restrict__ Vb)
{
  __shared__ char smem[49152];
  const float* A; const unsigned short* Bt; unsigned short* O;
  switch (blockIdx.z) {
    case 0:  A = X; Bt = WT;          O = Qb; break;
    case 1:  A = Y; Bt = WT + 65536;  O = Kb; break;
    default: A = F; Bt = WT + 131072; O = Vb; break;
  }
  const int row0 = blockIdx.x << 7;
  f32x4 acc[4][4];
  gemm_core<true>(A, nullptr, Bt, row0, smem, acc);
  const int lane = threadIdx.x & 63, wid = threadIdx.x >> 6;
  const int wm = (wid >> 2) << 6, wn = (wid & 3) << 6;
  const int fr = lane & 15, fq = (lane >> 4) << 2;
#pragma unroll
  for (int m = 0; m < 4; ++m)
#pragma unroll
    for (int n = 0; n < 4; ++n) {
      const int row = row0 + wm + m * 16 + fq;
      const int col = wn + n * 16 + fr;
#pragma unroll
      for (int r = 0; r < 4; ++r)
        O[(size_t)(row + r) * NC + col] = bfbits(acc[m][n][r]);
    }
}

__global__ __launch_bounds__(512) void out_mfma(const unsigned short* __restrict__ Vb,
                                                const unsigned short* __restrict__ WeffT,
                                                const float* __restrict__ bp, float* __restrict__ Out)
{
  __shared__ char smem[49152];
  const int row0 = blockIdx.x << 7;
  const unsigned short* Bt = WeffT + (size_t)(row0 >> 14) * NC * NC;
  f32x4 acc[4][4];
  gemm_core<false>(nullptr, Vb, Bt, row0, smem, acc);
  const int lane = threadIdx.x & 63, wid = threadIdx.x >> 6;
  const int wm = (wid >> 2) << 6, wn = (wid & 3) << 6;
  const int fr = lane & 15, fq = (lane >> 4) << 2;
#pragma unroll
  for (int m = 0; m < 4; ++m)
#pragma unroll
    for (int n = 0; n < 4; ++n) {
      const int row = row0 + wm + m * 16 + fq;
      const int col = wn + n * 16 + fr;
      const float bv = bp[col];
#pragma unroll
      for (int r = 0; r < 4; ++r)
        Out[(size_t)(row + r) * NC + col] = acc[m][n][r] + bv;
    }
}

// ---------- Gram G[b,h,i,j] = sum_n K[n,i]*Q[n,j], plus column norms (bf16 in, fp32 acc) ----------
__global__ __launch_bounds__(256) void gram(const unsigned short* __restrict__ Q, const unsigned short* __restrict__ K,
                                            float* __restrict__ G, float* __restrict__ qn, float* __restrict__ kn)
{
  const int bh = blockIdx.x;
  const int b = bh >> 3, h = bh & 7;
  const int n0 = blockIdx.y << 11;
  const unsigned short* Qb = Q + (size_t)b * NTOK * NC + h * DHEAD;
  const unsigned short* Kb = K + (size_t)b * NTOK * NC + h * DHEAD;
  __shared__ float qs[64][32];
  __shared__ float ks[64][32];
  const int t = threadIdx.x;
  const int i = t >> 3, j4 = (t & 7) << 2;
  const int sr = t >> 2, sc = (t & 3) << 3;
  float acc[4] = {0.f, 0.f, 0.f, 0.f};
  float q2[4] = {0.f, 0.f, 0.f, 0.f};
  float k2 = 0.f;
  for (int nb = 0; nb < 2048; nb += 64) {
    uint4 qu = *(const uint4*)&Qb[(size_t)(n0 + nb + sr) * NC + sc];
    uint4 ku = *(const uint4*)&Kb[(size_t)(n0 + nb + sr) * NC + sc];
    qs[sr][sc + 0] = bflo(qu.x); qs[sr][sc + 1] = bfhi(qu.x);
    qs[sr][sc + 2] = bflo(qu.y); qs[sr][sc + 3] = bfhi(qu.y);
    qs[sr][sc + 4] = bflo(qu.z); qs[sr][sc + 5] = bfhi(qu.z);
    qs[sr][sc + 6] = bflo(qu.w); qs[sr][sc + 7] = bfhi(qu.w);
    ks[sr][sc + 0] = bflo(ku.x); ks[sr][sc + 1] = bfhi(ku.x);
    ks[sr][sc + 2] = bflo(ku.y); ks[sr][sc + 3] = bfhi(ku.y);
    ks[sr][sc + 4] = bflo(ku.z); ks[sr][sc + 5] = bfhi(ku.z);
    ks[sr][sc + 6] = bflo(ku.w); ks[sr][sc + 7] = bfhi(ku.w);
    __syncthreads();
#pragma unroll 4
    for (int r = 0; r < 64; ++r) {
      float kv = ks[r][i];
      float4 qv = *(const float4*)&qs[r][j4];
      acc[0] = fmaf(kv, qv.x, acc[0]);
      acc[1] = fmaf(kv, qv.y, acc[1]);
      acc[2] = fmaf(kv, qv.z, acc[2]);
      acc[3] = fmaf(kv, qv.w, acc[3]);
      if (i == 0) {
        q2[0] = fmaf(qv.x, qv.x, q2[0]); q2[1] = fmaf(qv.y, qv.y, q2[1]);
        q2[2] = fmaf(qv.z, qv.z, q2[2]); q2[3] = fmaf(qv.w, qv.w, q2[3]);
      }
      if ((t & 7) == 0) k2 = fmaf(kv, kv, k2);
    }
    __syncthreads();
  }
  float* Gb = G + (size_t)(b * NHEADS + h) * DHEAD * DHEAD;
  atomicAdd(&Gb[i * DHEAD + j4 + 0], acc[0]);
  atomicAdd(&Gb[i * DHEAD + j4 + 1], acc[1]);
  atomicAdd(&Gb[i * DHEAD + j4 + 2], acc[2]);
  atomicAdd(&Gb[i * DHEAD + j4 + 3], acc[3]);
  if (i == 0) {
#pragma unroll
    for (int u = 0; u < 4; ++u) atomicAdd(&qn[b * NC + h * DHEAD + j4 + u], q2[u]);
  }
  if ((t & 7) == 0) atomicAdd(&kn[b * NC + h * DHEAD + i], k2);
}

// ---------- softmax + fold attn into Wp: WeffT[b][m][h*32+j] = sum_i A[h,i,j]*Wp[h*32+i][m] (bf16 out, TRANSPOSED) ----------
__global__ __launch_bounds__(256) void softmax_weff(const float* __restrict__ G, const float* __restrict__ qn,
                                                    const float* __restrict__ kn, const float* __restrict__ rescale,
                                                    const float* __restrict__ Wp, unsigned short* __restrict__ WeffT)
{
  const int b = blockIdx.x, h = blockIdx.y;
  __shared__ float Asm[32][33];
  __shared__ float WpS[32][256];
  const int t = threadIdx.x;
  const float rs = rescale[h];
  const float* Gb = G + (size_t)(b * NHEADS + h) * DHEAD * DHEAD;
#pragma unroll
  for (int l = 0; l < 4; ++l) {
    int idx = t + (l << 8);
    int i = idx >> 5, j = idx & 31;
    float knv = fmaxf(sqrtf(kn[b * NC + h * DHEAD + i]), 1e-12f);
    float qnv = fmaxf(sqrtf(qn[b * NC + h * DHEAD + j]), 1e-12f);
    Asm[i][j] = Gb[idx] / (knv * qnv) * rs;
  }
  __syncthreads();
  if (t < 32) {
    int i = t;
    float mx = -1e30f;
#pragma unroll
    for (int j = 0; j < 32; ++j) mx = fmaxf(mx, Asm[i][j]);
    float s = 0.f;
#pragma unroll
    for (int j = 0; j < 32; ++j) { float e = __expf(Asm[i][j] - mx); Asm[i][j] = e; s += e; }
    float inv = 1.f / s;
#pragma unroll
    for (int j = 0; j < 32; ++j) Asm[i][j] *= inv;
  }
#pragma unroll
  for (int l = 0; l < 8; ++l) {
    int idx = t + (l << 8);
    int r = idx >> 6;
    int c4 = (idx & 63) << 2;
    *(float4*)&WpS[r][c4] = *(const float4*)&Wp[(size_t)(h * DHEAD + r) * NC + c4];
  }
  __syncthreads();
  const int j = t & 31, mb = t >> 5;
  for (int mm = 0; mm < 32; ++mm) {
    int m = (mb << 5) + mm;
    float s = 0.f;
#pragma unroll
    for (int i = 0; i < 32; ++i) s = fmaf(Asm[i][j], WpS[i][m], s);
    WeffT[((size_t)b * NC + m) * NC + h * DHEAD + j] = bfbits(s);
  }
}

// ---------- depthwise 3x3 + exact GELU (bf16x2 packed) ----------
__global__ __launch_bounds__(256) void dw1_gelu(const unsigned* __restrict__ Vp, const float* __restrict__ pw1,
                                                unsigned* __restrict__ T)
{
  int idx = blockIdx.x * 256 + threadIdx.x;
  int c2 = idx & 127;
  int x = (idx >> 7) & 127;
  int y = (idx >> 14) & 127;
  int b = idx >> 21;
  float a0 = 0.f, a1 = 0.f;
#pragma unroll
  for (int ky = 0; ky < 3; ++ky) {
    int yy = y + ky - 1;
    if ((unsigned)yy >= 128u) continue;
#pragma unroll
    for (int kx = 0; kx < 3; ++kx) {
      int xx = x + kx - 1;
      if ((unsigned)xx >= 128u) continue;
      unsigned v = Vp[(((size_t)(b * 128 + yy) * 128 + xx) << 7) + c2];
      float2 wv = *(const float2*)&pw1[(ky * 3 + kx) * NC + (c2 << 1)];
      a0 = fmaf(bflo(v), wv.x, a0);
      a1 = fmaf(bfhi(v), wv.y, a1);
    }
  }
  a0 = 0.5f * a0 * (1.f + erff(a0 * 0.70710678118654752f));
  a1 = 0.5f * a1 * (1.f + erff(a1 * 0.70710678118654752f));
  T[idx] = (unsigned)bfbits(a0) | ((unsigned)bfbits(a1) << 16);
}

__global__ __launch_bounds__(256) void dw2_add(const unsigned* __restrict__ T, const float* __restrict__ pw2,
                                               float* __restrict__ Out)
{
  int idx = blockIdx.x * 256 + threadIdx.x;
  int c2 = idx & 127;
  int x = (idx >> 7) & 127;
  int y = (idx >> 14) & 127;
  int b = idx >> 21;
  float a0 = 0.f, a1 = 0.f;
#pragma unroll
  for (int ky = 0; ky < 3; ++ky) {
    int yy = y + ky - 1;
    if ((unsigned)yy >= 128u) continue;
#pragma unroll
    for (int kx = 0; kx < 3; ++kx) {
      int xx = x + kx - 1;
      if ((unsigned)xx >= 128u) continue;
      unsigned v = T[(((size_t)(b * 128 + yy) * 128 + xx) << 7) + c2];
      float2 wv = *(const float2*)&pw2[(ky * 3 + kx) * NC + (c2 << 1)];
      a0 = fmaf(bflo(v), wv.x, a0);
      a1 = fmaf(bfhi(v), wv.y, a1);
    }
  }
  float2* o = (float2*)&Out[((size_t)((b * 128 + y) * 128 + x)) * NC + (c2 << 1)];
  float2 cur = *o;
  cur.x += a0; cur.y += a1;
  *o = cur;
}

extern "C" void kernel_launch(void* const* d_in, const int* in_sizes, int n_in,
                              void* d_out, int out_size, void* d_ws, size_t ws_size,
                              hipStream_t stream)
{
  const float* x   = (const float*)d_in[0];
  const float* y   = (const float*)d_in[1];
  const float* f   = (const float*)d_in[2];
  const float* Wq  = (const float*)d_in[3];
  const float* Wk  = (const float*)d_in[4];
  const float* Wv  = (const float*)d_in[5];
  const float* rsc = (const float*)d_in[6];
  const float* Wp  = (const float*)d_in[7];
  const float* bp  = (const float*)d_in[8];
  const float* pw1 = (const float*)d_in[9];
  const float* pw2 = (const float*)d_in[10];
  float* out = (float*)d_out;

  char* w = (char*)d_ws;
  unsigned short* Qb = (unsigned short*)(w);                    // 33.5 MB
  unsigned short* Kb = (unsigned short*)(w + 33554432ull);
  unsigned short* Vb = (unsigned short*)(w + 67108864ull);
  float* G  = (float*)(w + 100663296ull);                       // 128 KB
  float* qn = (float*)(w + 100794368ull);                       // 4 KB
  float* kn = (float*)(w + 100798464ull);                       // 4 KB
  unsigned short* WeffT = (unsigned short*)(w + 100802560ull);  // 512 KB
  unsigned short* WT    = (unsigned short*)(w + 101326848ull);  // 384 KB
  unsigned* T = (unsigned*)Qb;  // reuse Q storage after gram()

  hipMemsetAsync(G, 0, 139264, stream);  // G + qn + kn

  prep_w<<<dim3(4, 4, 3), 256, 0, stream>>>(Wq, Wk, Wv, WT);
  qkv_mfma<<<dim3(512, 1, 3), 512, 0, stream>>>(x, y, f, WT, Qb, Kb, Vb);
  gram<<<dim3(32, 8), 256, 0, stream>>>(Qb, Kb, G, qn, kn);
  softmax_weff<<<dim3(NB, NHEADS), 256, 0, stream>>>(G, qn, kn, rsc, Wp, WeffT);
  dw1_gelu<<<32768, 256, 0, stream>>>((const unsigned*)Vb, pw1, T);
  out_mfma<<<512, 512, 0, stream>>>(Vb, WeffT, bp, out);
  dw2_add<<<32768, 256, 0, stream>>>(T, pw2, out);
}